// Round 1
// baseline (469.147 us; speedup 1.0000x reference)
//
#include <hip/hip_runtime.h>

// DEMA over x:(B=32, T=4096, F=512) fp32, scan along T.
// v_t = A v_{t-1} + c(x_t), A = [[1-a, 1-a], [-a*b, 1-a*b]] has |lambda| =
// sqrt(0.7) ~ 0.8367 -> ||A^128|| ~ 1.6e-9: a 128-step warmup from any
// bounded init reproduces the state to ~1e-8. So chunks of the time axis are
// independent given a halo -> fully parallel single kernel, no cross-block
// communication.

#define DEMA_ALPHA 0.3f
#define DEMA_BETA  0.1f
#define DEMA_T     4096
#define DEMA_B     32
#define DEMA_F     512
#define DEMA_L     256              // output chunk length
#define DEMA_H     128              // warmup halo length
#define DEMA_C     (DEMA_T / DEMA_L) // 16 chunks

__global__ __launch_bounds__(256) void dema_kernel(const float* __restrict__ x,
                                                   float* __restrict__ out) {
    const int f = blockIdx.x * blockDim.x + threadIdx.x;  // 0..511, coalesced
    const int b = blockIdx.y;                             // 0..31
    const int c = blockIdx.z;                             // 0..15 chunk idx

    const int base = (b * DEMA_T) * DEMA_F + f;           // < 2^31
    const float* xp = x + base;
    float* op = out + base;

    const float a1 = 1.0f - DEMA_ALPHA;   // 0.7
    const float b1 = 1.0f - DEMA_BETA;    // 0.9

    if (c == 0) {
        // Exact prefix: out_0 = s_0 = x_0; b_0 = x_1 - x_0; then recurrence.
        float s  = xp[0];
        float bb = xp[DEMA_F] - s;
        op[0] = s;
        #pragma unroll 4
        for (int t = 1; t < DEMA_L; ++t) {
            float xt = xp[t * DEMA_F];
            float sp = s;
            s  = DEMA_ALPHA * xt + a1 * (sp + bb);
            bb = DEMA_BETA * (s - sp) + b1 * bb;
            op[t * DEMA_F] = s;
        }
    } else {
        const int t0 = c * DEMA_L;       // >= 256
        const int tw = t0 - DEMA_H;      // >= 128 >= 1
        // Approximate state v_{tw-1}: s = x_{tw-1}, b = x_{tw} - x_{tw-1}.
        // Init error is O(few); after H=128 updates it is scaled by A^128
        // (~1.6e-9) -> negligible vs fp32 accumulation noise.
        float s  = xp[(tw - 1) * DEMA_F];
        float bb = xp[tw * DEMA_F] - s;
        #pragma unroll 4
        for (int t = tw; t < t0; ++t) {  // warmup, no writes
            float xt = xp[t * DEMA_F];
            float sp = s;
            s  = DEMA_ALPHA * xt + a1 * (sp + bb);
            bb = DEMA_BETA * (s - sp) + b1 * bb;
        }
        #pragma unroll 4
        for (int t = t0; t < t0 + DEMA_L; ++t) {
            float xt = xp[t * DEMA_F];
            float sp = s;
            s  = DEMA_ALPHA * xt + a1 * (sp + bb);
            bb = DEMA_BETA * (s - sp) + b1 * bb;
            op[t * DEMA_F] = s;
        }
    }
}

extern "C" void kernel_launch(void* const* d_in, const int* in_sizes, int n_in,
                              void* d_out, int out_size, void* d_ws, size_t ws_size,
                              hipStream_t stream) {
    const float* x = (const float*)d_in[0];
    float* out = (float*)d_out;

    dim3 block(256, 1, 1);
    dim3 grid(DEMA_F / 256, DEMA_B, DEMA_C);  // (2, 32, 16) = 1024 blocks
    dema_kernel<<<grid, block, 0, stream>>>(x, out);
}